// Round 5
// baseline (682.674 us; speedup 1.0000x reference)
//
#include <hip/hip_runtime.h>
#include <hip/hip_cooperative_groups.h>
#include <math.h>

namespace cg = cooperative_groups;

#define N_NODES  50000
#define N_EDGES  800000
#define E_TOT    (N_EDGES + N_NODES)   // 850000 incl self loops
#define N_GRAPHS 128
#define IN_F     768
#define HID2     128
#define NHID     64

typedef __attribute__((ext_vector_type(8))) short bf16x8;
typedef __attribute__((ext_vector_type(4))) float f32x4;
typedef __attribute__((ext_vector_type(4))) unsigned short us4;

__device__ __forceinline__ float selu_f(float x) {
    const float alpha = 1.6732632423543772f;
    const float scale = 1.0507009873554805f;
    return scale * (x > 0.f ? x : alpha * (expf(x) - 1.f));
}

// round-to-nearest-even fp32 -> bf16
__device__ __forceinline__ unsigned short f2bf(float f) {
    unsigned u = __float_as_uint(f);
    u += 0x7FFFu + ((u >> 16) & 1u);
    return (unsigned short)(u >> 16);
}
__device__ __forceinline__ float bflo(unsigned q) { return __uint_as_float(q << 16); }
__device__ __forceinline__ float bfhi(unsigned q) { return __uint_as_float(q & 0xffff0000u); }

// ---------------- setup: convert/transpose both weight matrices (weights only now) ----------------
__global__ void setup_w(const float* __restrict__ W1, const float* __restrict__ W2,
                        unsigned short* __restrict__ Wt1, unsigned short* __restrict__ Wt2) {
    int i = blockIdx.x * blockDim.x + threadIdx.x;
    if (i < 128 * IN_F) {
        int n = i / IN_F, k = i - n * IN_F;
        Wt1[i] = f2bf(W1[(long)k * 128 + n]);
    }
    if (i < 128 * HID2) {
        int n = i >> 7, k = i & 127;
        Wt2[i] = f2bf(W2[(long)k * 128 + n]);
    }
}

// ---------------- cooperative CSR build: zero -> hist -> wave-aggregated alloc -> scatter ----------------
// Slot ranges are allocated by atomic (unordered across nodes) — CSR order is irrelevant to the
// aggregation semantics. Self-loop seeded first in each range. counter aliases row_ptr[N_NODES].
__global__ __launch_bounds__(256) void csr_build(const int* __restrict__ ei,
        unsigned* __restrict__ deg, unsigned* __restrict__ row_ptr,
        unsigned* __restrict__ cursor, unsigned* __restrict__ csr_src,
        unsigned* __restrict__ counter) {
    cg::grid_group grid = cg::this_grid();
    const int tid  = blockIdx.x * blockDim.x + threadIdx.x;
    const int nthr = gridDim.x * blockDim.x;
    // P0: zero degree + counter
    for (int i = tid; i < N_NODES; i += nthr) deg[i] = 0u;
    if (tid == 0) *counter = 0u;
    grid.sync();
    // P1: degree histogram
    for (int e = tid; e < N_EDGES; e += nthr) atomicAdd(&deg[ei[N_EDGES + e]], 1u);
    grid.sync();
    // P2: wave-aggregated slot allocation + self-loop seed (N_NODES < nthr: single pass)
    {
        int lane = threadIdx.x & 63;
        int i = tid;
        unsigned v = (i < N_NODES) ? deg[i] + 1u : 0u;
        unsigned x = v;
        for (int o = 1; o < 64; o <<= 1) {
            unsigned y = __shfl_up(x, o);
            if (lane >= o) x += y;
        }
        unsigned wtot = __shfl(x, 63);
        unsigned base = 0u;
        if (lane == 0 && wtot) base = atomicAdd(counter, wtot);
        base = __shfl(base, 0);
        if (i < N_NODES) {
            unsigned rp = base + x - v;
            row_ptr[i] = rp;
            csr_src[rp] = (unsigned)i;   // self-loop first
            cursor[i] = rp + 1u;
        }
    }
    grid.sync();
    // P3: edge scatter
    for (int e = tid; e < N_EDGES; e += nthr) {
        int d = ei[N_EDGES + e];
        unsigned p = atomicAdd(&cursor[d], 1u);
        csr_src[p] = (unsigned)ei[e];
    }
}

// ---------------- GEMM: bf16 MFMA, M64/BK64, reg-prefetch; fused e_src/e_dst epilogue ----------------
// es/ed written DIRECTLY (LDS pair-combine across the two n-half waves) — no atomics, no zero-init.
#define LDA2 72   // padded LDS row stride (bf16): 144 B; frag reads conflict-free
template<bool ABF16, bool OUTBF16>
__global__ __launch_bounds__(256) void gemm_mfma(
        const void* __restrict__ Av, const unsigned short* __restrict__ Bt,
        void* __restrict__ Cv, int M, int K,
        const float* __restrict__ a_s, const float* __restrict__ a_d,
        float* __restrict__ es, float* __restrict__ ed) {
    __shared__ unsigned short As[64 * LDA2];    // 9.2 KB
    __shared__ unsigned short Bs[128 * LDA2];   // 18.4 KB
    __shared__ float es_s[2][64];
    __shared__ float ed_s[2][64];
    const float* Af = (const float*)Av;
    const unsigned short* Ab = (const unsigned short*)Av;
    const int tid  = threadIdx.x;
    const int row0 = blockIdx.x * 64;
    const int w    = tid >> 6;
    const int lane = tid & 63;
    const int quad = lane >> 4;
    const int l16  = lane & 15;
    const int m_off = (w & 1) * 32;   // wave covers 32 rows
    const int n_off = (w >> 1) * 64;  // x 64 cols
    const int nh    = w >> 1;

    f32x4 acc[2][4];
#pragma unroll
    for (int mi = 0; mi < 2; mi++)
#pragma unroll
        for (int ni = 0; ni < 4; ni++)
            acc[mi][ni] = (f32x4){0.f, 0.f, 0.f, 0.f};

    float4 aR[4];
    bf16x8 aRb[2];
    bf16x8 bR[4];
    if (ABF16) {
#pragma unroll
        for (int i = 0; i < 2; i++) {
            int p = tid + i * 256;
            int r = p >> 3, c8 = p & 7;
            int gr = row0 + r;
            aRb[i] = (gr < M) ? *(const bf16x8*)&Ab[(long)gr * K + c8 * 8]
                              : (bf16x8){0,0,0,0,0,0,0,0};
        }
    } else {
#pragma unroll
        for (int i = 0; i < 4; i++) {
            int p = tid + i * 256;
            int r = p >> 4, c4 = p & 15;
            int gr = row0 + r;
            aR[i] = (gr < M) ? *(const float4*)&Af[(long)gr * K + c4 * 4]
                             : make_float4(0.f, 0.f, 0.f, 0.f);
        }
    }
#pragma unroll
    for (int i = 0; i < 4; i++) {
        int c = tid + i * 256;
        int n = c >> 3, koff = (c & 7) * 8;
        bR[i] = *(const bf16x8*)&Bt[(long)n * K + koff];
    }

    for (int k0 = 0; k0 < K; k0 += 64) {
        if (ABF16) {
#pragma unroll
            for (int i = 0; i < 2; i++) {
                int p = tid + i * 256;
                int r = p >> 3, c8 = p & 7;
                *(bf16x8*)&As[r * LDA2 + c8 * 8] = aRb[i];
            }
        } else {
#pragma unroll
            for (int i = 0; i < 4; i++) {
                int p = tid + i * 256;
                int r = p >> 4, c4 = p & 15;
                us4 o;
                o.x = f2bf(aR[i].x); o.y = f2bf(aR[i].y);
                o.z = f2bf(aR[i].z); o.w = f2bf(aR[i].w);
                *(us4*)&As[r * LDA2 + c4 * 4] = o;
            }
        }
#pragma unroll
        for (int i = 0; i < 4; i++) {
            int c = tid + i * 256;
            int n = c >> 3, koff = (c & 7) * 8;
            *(bf16x8*)&Bs[n * LDA2 + koff] = bR[i];
        }
        __syncthreads();

        if (k0 + 64 < K) {
            int k1 = k0 + 64;
            if (ABF16) {
#pragma unroll
                for (int i = 0; i < 2; i++) {
                    int p = tid + i * 256;
                    int r = p >> 3, c8 = p & 7;
                    int gr = row0 + r;
                    aRb[i] = (gr < M) ? *(const bf16x8*)&Ab[(long)gr * K + k1 + c8 * 8]
                                      : (bf16x8){0,0,0,0,0,0,0,0};
                }
            } else {
#pragma unroll
                for (int i = 0; i < 4; i++) {
                    int p = tid + i * 256;
                    int r = p >> 4, c4 = p & 15;
                    int gr = row0 + r;
                    aR[i] = (gr < M) ? *(const float4*)&Af[(long)gr * K + k1 + c4 * 4]
                                     : make_float4(0.f, 0.f, 0.f, 0.f);
                }
            }
#pragma unroll
            for (int i = 0; i < 4; i++) {
                int c = tid + i * 256;
                int n = c >> 3, koff = (c & 7) * 8;
                bR[i] = *(const bf16x8*)&Bt[(long)n * K + k1 + koff];
            }
        }

        bf16x8 af[2][2], bfr[2][4];
#pragma unroll
        for (int kk = 0; kk < 2; kk++) {
#pragma unroll
            for (int mi = 0; mi < 2; mi++)
                af[kk][mi] = *(const bf16x8*)&As[(m_off + mi * 16 + l16) * LDA2 + kk * 32 + quad * 8];
#pragma unroll
            for (int ni = 0; ni < 4; ni++)
                bfr[kk][ni] = *(const bf16x8*)&Bs[(n_off + ni * 16 + l16) * LDA2 + kk * 32 + quad * 8];
        }
#pragma unroll
        for (int kk = 0; kk < 2; kk++)
#pragma unroll
            for (int mi = 0; mi < 2; mi++)
#pragma unroll
                for (int ni = 0; ni < 4; ni++)
                    acc[mi][ni] = __builtin_amdgcn_mfma_f32_16x16x32_bf16(
                        af[kk][mi], bfr[kk][ni], acc[mi][ni], 0, 0, 0);
        __syncthreads();
    }

    // attention-vector partials for this lane's 4 cols
    float as_v[4], ad_v[4];
#pragma unroll
    for (int ni = 0; ni < 4; ni++) {
        int col = n_off + ni * 16 + l16;
        as_v[ni] = a_s[col];
        ad_v[ni] = a_d[col];
    }

    // epilogue: D row = m_off+mi*16+quad*4+r, col = n_off+ni*16+l16
#pragma unroll
    for (int mi = 0; mi < 2; mi++)
#pragma unroll
        for (int r = 0; r < 4; r++) {
            int rl  = m_off + mi * 16 + quad * 4 + r;
            int row = row0 + rl;
            float ps = 0.f, pd = 0.f;
#pragma unroll
            for (int ni = 0; ni < 4; ni++) {
                float v = acc[mi][ni][r];
                ps = fmaf(v, as_v[ni], ps);
                pd = fmaf(v, ad_v[ni], pd);
            }
#pragma unroll
            for (int o = 1; o < 16; o <<= 1) {
                ps += __shfl_xor(ps, o);
                pd += __shfl_xor(pd, o);
            }
            if (l16 == 0) {
                es_s[nh][rl] = ps;
                ed_s[nh][rl] = pd;
            }
            if (row < M) {
                if (OUTBF16) {
                    unsigned short* C16 = (unsigned short*)Cv;
#pragma unroll
                    for (int ni = 0; ni < 4; ni++)
                        C16[(long)row * 128 + n_off + ni * 16 + l16] = f2bf(acc[mi][ni][r]);
                } else {
                    float* Cf = (float*)Cv;
#pragma unroll
                    for (int ni = 0; ni < 4; ni++)
                        Cf[(long)row * 128 + n_off + ni * 16 + l16] = acc[mi][ni][r];
                }
            }
        }
    __syncthreads();
    if (tid < 64) {
        int row = row0 + tid;
        if (row < M) {
            es[row] = es_s[0][tid] + es_s[1][tid];
            ed[row] = ed_s[0][tid] + ed_s[1][tid];
        }
    }
}

// ---------------- fused GAT tail: one node per HALF-WAVE, unroll-8 row gathers (R2 form) ----------------
template<bool OUTBF16>
__global__ __launch_bounds__(256) void gat_agg(
        const unsigned* __restrict__ row_ptr, const unsigned* __restrict__ deg_a,
        const unsigned* __restrict__ csr_src,
        const float* __restrict__ e_src, const float* __restrict__ e_dst,
        const unsigned short* __restrict__ xw, const float* __restrict__ bias,
        void* __restrict__ outv) {
    __shared__ float2 buf[8][32];     // (num, src-bits) per half-wave
    int hw = threadIdx.x >> 5;        // half-wave id 0..7
    int node = blockIdx.x * 8 + hw;
    if (node >= N_NODES) return;
    int fl = threadIdx.x & 31;
    unsigned beg = row_ptr[node];
    int deg = (int)deg_a[node] + 1;   // incl self loop
    float ed = e_dst[node];
    const unsigned short* xwf = xw + fl * 4;

    float ax = 0.f, ay = 0.f, az = 0.f, aw = 0.f, den = 0.f;
    for (int base = 0; base < deg; base += 32) {
        int i = base + fl;
        float num = 0.f;
        unsigned s = 0u;
        if (i < deg) {
            s = csr_src[beg + i];
            float e = e_src[s] + ed;
            e = e > 0.f ? e : 0.2f * e;
            num = __expf(e);
            den += num;
        }
        float2 pk; pk.x = num; pk.y = __uint_as_float(s);
        buf[hw][fl] = pk;

        int cnt = deg - base; if (cnt > 32) cnt = 32;
        int t = 0;
        for (; t + 8 <= cnt; t += 8) {
            float2 p0 = buf[hw][t + 0];
            float2 p1 = buf[hw][t + 1];
            float2 p2 = buf[hw][t + 2];
            float2 p3 = buf[hw][t + 3];
            float2 p4 = buf[hw][t + 4];
            float2 p5 = buf[hw][t + 5];
            float2 p6 = buf[hw][t + 6];
            float2 p7 = buf[hw][t + 7];
            uint2 q0 = *(const uint2*)&xwf[(long)__float_as_uint(p0.y) * HID2];
            uint2 q1 = *(const uint2*)&xwf[(long)__float_as_uint(p1.y) * HID2];
            uint2 q2 = *(const uint2*)&xwf[(long)__float_as_uint(p2.y) * HID2];
            uint2 q3 = *(const uint2*)&xwf[(long)__float_as_uint(p3.y) * HID2];
            uint2 q4 = *(const uint2*)&xwf[(long)__float_as_uint(p4.y) * HID2];
            uint2 q5 = *(const uint2*)&xwf[(long)__float_as_uint(p5.y) * HID2];
            uint2 q6 = *(const uint2*)&xwf[(long)__float_as_uint(p6.y) * HID2];
            uint2 q7 = *(const uint2*)&xwf[(long)__float_as_uint(p7.y) * HID2];
            ax = fmaf(p0.x, bflo(q0.x), ax); ay = fmaf(p0.x, bfhi(q0.x), ay);
            az = fmaf(p0.x, bflo(q0.y), az); aw = fmaf(p0.x, bfhi(q0.y), aw);
            ax = fmaf(p1.x, bflo(q1.x), ax); ay = fmaf(p1.x, bfhi(q1.x), ay);
            az = fmaf(p1.x, bflo(q1.y), az); aw = fmaf(p1.x, bfhi(q1.y), aw);
            ax = fmaf(p2.x, bflo(q2.x), ax); ay = fmaf(p2.x, bfhi(q2.x), ay);
            az = fmaf(p2.x, bflo(q2.y), az); aw = fmaf(p2.x, bfhi(q2.y), aw);
            ax = fmaf(p3.x, bflo(q3.x), ax); ay = fmaf(p3.x, bfhi(q3.x), ay);
            az = fmaf(p3.x, bflo(q3.y), az); aw = fmaf(p3.x, bfhi(q3.y), aw);
            ax = fmaf(p4.x, bflo(q4.x), ax); ay = fmaf(p4.x, bfhi(q4.x), ay);
            az = fmaf(p4.x, bflo(q4.y), az); aw = fmaf(p4.x, bfhi(q4.y), aw);
            ax = fmaf(p5.x, bflo(q5.x), ax); ay = fmaf(p5.x, bfhi(q5.x), ay);
            az = fmaf(p5.x, bflo(q5.y), az); aw = fmaf(p5.x, bfhi(q5.y), aw);
            ax = fmaf(p6.x, bflo(q6.x), ax); ay = fmaf(p6.x, bfhi(q6.x), ay);
            az = fmaf(p6.x, bflo(q6.y), az); aw = fmaf(p6.x, bfhi(q6.y), aw);
            ax = fmaf(p7.x, bflo(q7.x), ax); ay = fmaf(p7.x, bfhi(q7.x), ay);
            az = fmaf(p7.x, bflo(q7.y), az); aw = fmaf(p7.x, bfhi(q7.y), aw);
        }
        for (; t < cnt; t++) {
            float2 p = buf[hw][t];
            uint2 q = *(const uint2*)&xwf[(long)__float_as_uint(p.y) * HID2];
            ax = fmaf(p.x, bflo(q.x), ax); ay = fmaf(p.x, bfhi(q.x), ay);
            az = fmaf(p.x, bflo(q.y), az); aw = fmaf(p.x, bfhi(q.y), aw);
        }
    }
    // reduce den across the 32 lanes of this half-wave
    for (int o = 16; o; o >>= 1) den += __shfl_xor(den, o);
    float inv = 1.f / den;
    float v0 = selu_f(fmaf(ax, inv, bias[fl * 4 + 0]));
    float v1 = selu_f(fmaf(ay, inv, bias[fl * 4 + 1]));
    float v2 = selu_f(fmaf(az, inv, bias[fl * 4 + 2]));
    float v3 = selu_f(fmaf(aw, inv, bias[fl * 4 + 3]));
    if (OUTBF16) {
        uint2 o;
        o.x = ((unsigned)f2bf(v1) << 16) | (unsigned)f2bf(v0);
        o.y = ((unsigned)f2bf(v3) << 16) | (unsigned)f2bf(v2);
        *(uint2*)((unsigned short*)outv + (long)node * HID2 + fl * 4) = o;
    } else {
        float4 o = make_float4(v0, v1, v2, v3);
        *(float4*)((float*)outv + (long)node * HID2 + fl * 4) = o;
    }
}

// ---------------- fused pool + fc1 + fc2 + log_softmax: one block per graph ----------------
__global__ __launch_bounds__(256) void pool_head(
        const float* __restrict__ h, const int* __restrict__ batch,
        const float* __restrict__ fc1w, const float* __restrict__ fc1b,
        const float* __restrict__ fc2w, const float* __restrict__ fc2b,
        float* __restrict__ out) {
    __shared__ float pooled_s[HID2];
    __shared__ float part[HID2];
    __shared__ float g_s[NHID];
    int g = blockIdx.x;
    int lo = 0, hi = N_NODES;
    while (lo < hi) { int mid = (lo + hi) >> 1; if (batch[mid] < g) lo = mid + 1; else hi = mid; }
    int start = lo;
    hi = N_NODES;
    while (lo < hi) { int mid = (lo + hi) >> 1; if (batch[mid] < g + 1) lo = mid + 1; else hi = mid; }
    int end = lo;

    int f = threadIdx.x & 127, half = threadIdx.x >> 7;
    float acc = 0.f;
    for (int n = start + half; n < end; n += 2) acc += h[(long)n * HID2 + f];
    if (half == 0) part[f] = acc;
    __syncthreads();
    if (half == 1) {
        float c = (float)(end - start);
        c = c > 1.f ? c : 1.f;
        pooled_s[f] = selu_f((part[f] + acc) / c);
    }
    __syncthreads();
    int j = threadIdx.x;
    if (j < NHID) {
        float a = fc1b[j];
#pragma unroll
        for (int k = 0; k < HID2; k++) a = fmaf(pooled_s[k], fc1w[k * NHID + j], a);
        g_s[j] = selu_f(a);
    }
    __syncthreads();
    if (j == 0) {
        float l0 = fc2b[0], l1 = fc2b[1];
#pragma unroll
        for (int k = 0; k < NHID; k++) {
            float v = g_s[k];
            l0 = fmaf(v, fc2w[2 * k + 0], l0);
            l1 = fmaf(v, fc2w[2 * k + 1], l1);
        }
        float m = fmaxf(l0, l1);
        float lse = m + logf(expf(l0 - m) + expf(l1 - m));
        out[g * 2 + 0] = l0 - lse;
        out[g * 2 + 1] = l1 - lse;
    }
}

extern "C" void kernel_launch(void* const* d_in, const int* in_sizes, int n_in,
                              void* d_out, int out_size, void* d_ws, size_t ws_size,
                              hipStream_t stream) {
    const float* x     = (const float*)d_in[0];
    const int*   ei    = (const int*)d_in[1];
    const int*   batch = (const int*)d_in[2];
    const float* W1    = (const float*)d_in[3];
    const float* as1   = (const float*)d_in[4];
    const float* ad1   = (const float*)d_in[5];
    const float* b1    = (const float*)d_in[6];
    const float* W2    = (const float*)d_in[7];
    const float* as2   = (const float*)d_in[8];
    const float* ad2   = (const float*)d_in[9];
    const float* b2    = (const float*)d_in[10];
    const float* fc1w  = (const float*)d_in[11];
    const float* fc1b  = (const float*)d_in[12];
    const float* fc2w  = (const float*)d_in[13];
    const float* fc2b  = (const float*)d_in[14];
    float* out = (float*)d_out;

    // workspace layout
    const long NH = (long)N_NODES * HID2;        // 6.4M elems
    unsigned short* xwb = (unsigned short*)d_ws;         // NH bf16 (xw, row-major, both layers)
    unsigned short* h1b = xwb + NH;                      // NH bf16 (h1, row-major)
    float*    B2      = (float*)(h1b + NH);              // NH f32 (h2, row-major, for pooling)
    float*    es1     = B2 + NH;
    float*    ed1     = es1 + N_NODES;
    float*    es2     = ed1 + N_NODES;
    float*    ed2     = es2 + N_NODES;
    unsigned* deg     = (unsigned*)(ed2 + N_NODES);
    unsigned* cursor  = deg + N_NODES;
    unsigned* row_ptr = cursor + N_NODES;               // N_NODES+1 (last slot = alloc counter)
    unsigned* csr_src = row_ptr + N_NODES + 1;          // E_TOT
    unsigned short* Wt1 = (unsigned short*)(csr_src + E_TOT);  // 128x768 bf16
    unsigned short* Wt2 = Wt1 + 128 * IN_F;                    // 128x128 bf16
    unsigned* counter = row_ptr + N_NODES;

    const int TB = 256;
    const int gGemm = (N_NODES + 63) / 64;
    const int gAgg  = (N_NODES + 7) / 8;

    // weight conversion + cooperative CSR build (1 dispatch replaces zero/hist/scan/scatter chain)
    setup_w<<<(128 * IN_F + TB - 1) / TB, TB, 0, stream>>>(W1, W2, Wt1, Wt2);
    {
        void* args[] = {(void*)&ei, (void*)&deg, (void*)&row_ptr, (void*)&cursor,
                        (void*)&csr_src, (void*)&counter};
        hipLaunchCooperativeKernel((void*)csr_build, dim3(512), dim3(TB), args, 0, stream);
    }

    // ---- layer 1 ----
    gemm_mfma<false, true><<<gGemm, 256, 0, stream>>>(x, Wt1, xwb, N_NODES, IN_F,
                                                      as1, ad1, es1, ed1);
    gat_agg<true><<<gAgg, TB, 0, stream>>>(row_ptr, deg, csr_src, es1, ed1, xwb, b1, h1b);

    // ---- layer 2 ----
    gemm_mfma<true, true><<<gGemm, 256, 0, stream>>>(h1b, Wt2, xwb, N_NODES, HID2,
                                                     as2, ad2, es2, ed2);
    gat_agg<false><<<gAgg, TB, 0, stream>>>(row_ptr, deg, csr_src, es2, ed2, xwb, b2, B2);

    // ---- pool + head (fused) ----
    pool_head<<<N_GRAPHS, 256, 0, stream>>>(B2, batch, fc1w, fc1b, fc2w, fc2b, out);
}

// Round 6
// 526.336 us; speedup vs baseline: 1.2970x; 1.2970x over previous
//
#include <hip/hip_runtime.h>
#include <math.h>

#define N_NODES  50000
#define N_EDGES  800000
#define E_TOT    (N_EDGES + N_NODES)   // 850000 incl self loops
#define N_GRAPHS 128
#define IN_F     768
#define HID2     128
#define NHID     64

typedef __attribute__((ext_vector_type(8))) short bf16x8;
typedef __attribute__((ext_vector_type(4))) float f32x4;
typedef __attribute__((ext_vector_type(4))) unsigned short us4;

__device__ __forceinline__ float selu_f(float x) {
    const float alpha = 1.6732632423543772f;
    const float scale = 1.0507009873554805f;
    return scale * (x > 0.f ? x : alpha * (expf(x) - 1.f));
}

// round-to-nearest-even fp32 -> bf16
__device__ __forceinline__ unsigned short f2bf(float f) {
    unsigned u = __float_as_uint(f);
    u += 0x7FFFu + ((u >> 16) & 1u);
    return (unsigned short)(u >> 16);
}
__device__ __forceinline__ float bflo(unsigned q) { return __uint_as_float(q << 16); }
__device__ __forceinline__ float bfhi(unsigned q) { return __uint_as_float(q & 0xffff0000u); }

// ---------------- setup: zero deg, convert/transpose both weight matrices ----------------
__global__ void setup_k(const float* __restrict__ W1, const float* __restrict__ W2,
                        unsigned short* __restrict__ Wt1, unsigned short* __restrict__ Wt2,
                        unsigned* __restrict__ deg) {
    int i = blockIdx.x * blockDim.x + threadIdx.x;
    if (i < N_NODES) deg[i] = 0u;
    if (i < 128 * IN_F) {
        int n = i / IN_F, k = i - n * IN_F;
        Wt1[i] = f2bf(W1[(long)k * 128 + n]);
    }
    if (i < 128 * HID2) {
        int n = i >> 7, k = i & 127;
        Wt2[i] = f2bf(W2[(long)k * 128 + n]);
    }
}

// ---------------- GEMM: bf16 MFMA, M64/BK64, reg-prefetch; fused e_src/e_dst epilogue ----------------
// es/ed written DIRECTLY (LDS pair-combine across the two n-half waves) — no atomics, no zero-init.
#define LDA2 72   // padded LDS row stride (bf16): 144 B; frag reads conflict-free
template<bool ABF16, bool OUTBF16>
__global__ __launch_bounds__(256) void gemm_mfma(
        const void* __restrict__ Av, const unsigned short* __restrict__ Bt,
        void* __restrict__ Cv, int M, int K,
        const float* __restrict__ a_s, const float* __restrict__ a_d,
        float* __restrict__ es, float* __restrict__ ed) {
    __shared__ unsigned short As[64 * LDA2];    // 9.2 KB
    __shared__ unsigned short Bs[128 * LDA2];   // 18.4 KB
    __shared__ float es_s[2][64];
    __shared__ float ed_s[2][64];
    const float* Af = (const float*)Av;
    const unsigned short* Ab = (const unsigned short*)Av;
    const int tid  = threadIdx.x;
    const int row0 = blockIdx.x * 64;
    const int w    = tid >> 6;
    const int lane = tid & 63;
    const int quad = lane >> 4;
    const int l16  = lane & 15;
    const int m_off = (w & 1) * 32;   // wave covers 32 rows
    const int n_off = (w >> 1) * 64;  // x 64 cols
    const int nh    = w >> 1;

    f32x4 acc[2][4];
#pragma unroll
    for (int mi = 0; mi < 2; mi++)
#pragma unroll
        for (int ni = 0; ni < 4; ni++)
            acc[mi][ni] = (f32x4){0.f, 0.f, 0.f, 0.f};

    float4 aR[4];
    bf16x8 aRb[2];
    bf16x8 bR[4];
    if (ABF16) {
#pragma unroll
        for (int i = 0; i < 2; i++) {
            int p = tid + i * 256;
            int r = p >> 3, c8 = p & 7;
            int gr = row0 + r;
            aRb[i] = (gr < M) ? *(const bf16x8*)&Ab[(long)gr * K + c8 * 8]
                              : (bf16x8){0,0,0,0,0,0,0,0};
        }
    } else {
#pragma unroll
        for (int i = 0; i < 4; i++) {
            int p = tid + i * 256;
            int r = p >> 4, c4 = p & 15;
            int gr = row0 + r;
            aR[i] = (gr < M) ? *(const float4*)&Af[(long)gr * K + c4 * 4]
                             : make_float4(0.f, 0.f, 0.f, 0.f);
        }
    }
#pragma unroll
    for (int i = 0; i < 4; i++) {
        int c = tid + i * 256;
        int n = c >> 3, koff = (c & 7) * 8;
        bR[i] = *(const bf16x8*)&Bt[(long)n * K + koff];
    }

    for (int k0 = 0; k0 < K; k0 += 64) {
        if (ABF16) {
#pragma unroll
            for (int i = 0; i < 2; i++) {
                int p = tid + i * 256;
                int r = p >> 3, c8 = p & 7;
                *(bf16x8*)&As[r * LDA2 + c8 * 8] = aRb[i];
            }
        } else {
#pragma unroll
            for (int i = 0; i < 4; i++) {
                int p = tid + i * 256;
                int r = p >> 4, c4 = p & 15;
                us4 o;
                o.x = f2bf(aR[i].x); o.y = f2bf(aR[i].y);
                o.z = f2bf(aR[i].z); o.w = f2bf(aR[i].w);
                *(us4*)&As[r * LDA2 + c4 * 4] = o;
            }
        }
#pragma unroll
        for (int i = 0; i < 4; i++) {
            int c = tid + i * 256;
            int n = c >> 3, koff = (c & 7) * 8;
            *(bf16x8*)&Bs[n * LDA2 + koff] = bR[i];
        }
        __syncthreads();

        if (k0 + 64 < K) {
            int k1 = k0 + 64;
            if (ABF16) {
#pragma unroll
                for (int i = 0; i < 2; i++) {
                    int p = tid + i * 256;
                    int r = p >> 3, c8 = p & 7;
                    int gr = row0 + r;
                    aRb[i] = (gr < M) ? *(const bf16x8*)&Ab[(long)gr * K + k1 + c8 * 8]
                                      : (bf16x8){0,0,0,0,0,0,0,0};
                }
            } else {
#pragma unroll
                for (int i = 0; i < 4; i++) {
                    int p = tid + i * 256;
                    int r = p >> 4, c4 = p & 15;
                    int gr = row0 + r;
                    aR[i] = (gr < M) ? *(const float4*)&Af[(long)gr * K + k1 + c4 * 4]
                                     : make_float4(0.f, 0.f, 0.f, 0.f);
                }
            }
#pragma unroll
            for (int i = 0; i < 4; i++) {
                int c = tid + i * 256;
                int n = c >> 3, koff = (c & 7) * 8;
                bR[i] = *(const bf16x8*)&Bt[(long)n * K + k1 + koff];
            }
        }

        bf16x8 af[2][2], bfr[2][4];
#pragma unroll
        for (int kk = 0; kk < 2; kk++) {
#pragma unroll
            for (int mi = 0; mi < 2; mi++)
                af[kk][mi] = *(const bf16x8*)&As[(m_off + mi * 16 + l16) * LDA2 + kk * 32 + quad * 8];
#pragma unroll
            for (int ni = 0; ni < 4; ni++)
                bfr[kk][ni] = *(const bf16x8*)&Bs[(n_off + ni * 16 + l16) * LDA2 + kk * 32 + quad * 8];
        }
#pragma unroll
        for (int kk = 0; kk < 2; kk++)
#pragma unroll
            for (int mi = 0; mi < 2; mi++)
#pragma unroll
                for (int ni = 0; ni < 4; ni++)
                    acc[mi][ni] = __builtin_amdgcn_mfma_f32_16x16x32_bf16(
                        af[kk][mi], bfr[kk][ni], acc[mi][ni], 0, 0, 0);
        __syncthreads();
    }

    // attention-vector partials for this lane's 4 cols
    float as_v[4], ad_v[4];
#pragma unroll
    for (int ni = 0; ni < 4; ni++) {
        int col = n_off + ni * 16 + l16;
        as_v[ni] = a_s[col];
        ad_v[ni] = a_d[col];
    }

    // epilogue: D row = m_off+mi*16+quad*4+r, col = n_off+ni*16+l16
#pragma unroll
    for (int mi = 0; mi < 2; mi++)
#pragma unroll
        for (int r = 0; r < 4; r++) {
            int rl  = m_off + mi * 16 + quad * 4 + r;
            int row = row0 + rl;
            float ps = 0.f, pd = 0.f;
#pragma unroll
            for (int ni = 0; ni < 4; ni++) {
                float v = acc[mi][ni][r];
                ps = fmaf(v, as_v[ni], ps);
                pd = fmaf(v, ad_v[ni], pd);
            }
#pragma unroll
            for (int o = 1; o < 16; o <<= 1) {
                ps += __shfl_xor(ps, o);
                pd += __shfl_xor(pd, o);
            }
            if (l16 == 0) {
                es_s[nh][rl] = ps;
                ed_s[nh][rl] = pd;
            }
            if (row < M) {
                if (OUTBF16) {
                    unsigned short* C16 = (unsigned short*)Cv;
#pragma unroll
                    for (int ni = 0; ni < 4; ni++)
                        C16[(long)row * 128 + n_off + ni * 16 + l16] = f2bf(acc[mi][ni][r]);
                } else {
                    float* Cf = (float*)Cv;
#pragma unroll
                    for (int ni = 0; ni < 4; ni++)
                        Cf[(long)row * 128 + n_off + ni * 16 + l16] = acc[mi][ni][r];
                }
            }
        }
    __syncthreads();
    if (tid < 64) {
        int row = row0 + tid;
        if (row < M) {
            es[row] = es_s[0][tid] + es_s[1][tid];
            ed[row] = ed_s[0][tid] + ed_s[1][tid];
        }
    }
}

// ---------------- CSR build (4-kernel chain, measured ~85 µs total) ----------------
__global__ void deg_hist(const int* __restrict__ ei, unsigned* __restrict__ deg) {
    int e = blockIdx.x * blockDim.x + threadIdx.x;
    if (e < N_EDGES) atomicAdd(&deg[ei[N_EDGES + e]], 1u);
}

// exclusive scan of (deg+1) -> row_ptr, fused with self-loop seed + cursor init.
__global__ __launch_bounds__(256) void scan_seed(const unsigned* __restrict__ deg,
                                                 unsigned* __restrict__ row_ptr,
                                                 unsigned* __restrict__ cursor,
                                                 unsigned* __restrict__ csr_src) {
    __shared__ unsigned psum_s[4];
    __shared__ unsigned wsum[4];
    int tid = threadIdx.x;
    int wid = tid >> 6, lane = tid & 63;
    int chunk0 = blockIdx.x * 256;

    unsigned psum = 0;
    for (int i = tid; i < chunk0; i += 256) psum += deg[i] + 1u;
    for (int o = 32; o; o >>= 1) psum += __shfl_xor(psum, o);
    if (lane == 0) psum_s[wid] = psum;

    int i = chunk0 + tid;
    unsigned v = (i < N_NODES) ? deg[i] + 1u : 0u;
    unsigned x = v;
    for (int o = 1; o < 64; o <<= 1) {
        unsigned y = __shfl_up(x, o);
        if (lane >= o) x += y;
    }
    if (lane == 63) wsum[wid] = x;
    __syncthreads();
    unsigned base = psum_s[0] + psum_s[1] + psum_s[2] + psum_s[3];
    unsigned wbase = 0;
    for (int k = 0; k < wid; k++) wbase += wsum[k];
    if (i < N_NODES) {
        unsigned rp = base + wbase + x - v;
        row_ptr[i] = rp;
        csr_src[rp] = (unsigned)i;   // self-loop first
        cursor[i] = rp + 1;
        if (i == N_NODES - 1) row_ptr[N_NODES] = rp + v;
    }
}

__global__ void csr_scatter(const int* __restrict__ ei,
                            unsigned* __restrict__ cursor, unsigned* __restrict__ csr_src) {
    int e = blockIdx.x * blockDim.x + threadIdx.x;
    if (e >= N_EDGES) return;
    int d = ei[N_EDGES + e];
    unsigned p = atomicAdd(&cursor[d], 1u);
    csr_src[p] = (unsigned)ei[e];
}

// ---------------- fused GAT tail: one node per HALF-WAVE, unroll-8 row gathers (R2 form) ----------------
template<bool OUTBF16>
__global__ __launch_bounds__(256) void gat_agg(
        const unsigned* __restrict__ row_ptr, const unsigned* __restrict__ csr_src,
        const float* __restrict__ e_src, const float* __restrict__ e_dst,
        const unsigned short* __restrict__ xw, const float* __restrict__ bias,
        void* __restrict__ outv) {
    __shared__ float2 buf[8][32];     // (num, src-bits) per half-wave
    int hw = threadIdx.x >> 5;        // half-wave id 0..7
    int node = blockIdx.x * 8 + hw;
    if (node >= N_NODES) return;
    int fl = threadIdx.x & 31;
    unsigned beg = row_ptr[node];
    int deg = (int)(row_ptr[node + 1] - beg);
    float ed = e_dst[node];
    const unsigned short* xwf = xw + fl * 4;

    float ax = 0.f, ay = 0.f, az = 0.f, aw = 0.f, den = 0.f;
    for (int base = 0; base < deg; base += 32) {
        int i = base + fl;
        float num = 0.f;
        unsigned s = 0u;
        if (i < deg) {
            s = csr_src[beg + i];
            float e = e_src[s] + ed;
            e = e > 0.f ? e : 0.2f * e;
            num = __expf(e);
            den += num;
        }
        float2 pk; pk.x = num; pk.y = __uint_as_float(s);
        buf[hw][fl] = pk;

        int cnt = deg - base; if (cnt > 32) cnt = 32;
        int t = 0;
        for (; t + 8 <= cnt; t += 8) {
            float2 p0 = buf[hw][t + 0];
            float2 p1 = buf[hw][t + 1];
            float2 p2 = buf[hw][t + 2];
            float2 p3 = buf[hw][t + 3];
            float2 p4 = buf[hw][t + 4];
            float2 p5 = buf[hw][t + 5];
            float2 p6 = buf[hw][t + 6];
            float2 p7 = buf[hw][t + 7];
            uint2 q0 = *(const uint2*)&xwf[(long)__float_as_uint(p0.y) * HID2];
            uint2 q1 = *(const uint2*)&xwf[(long)__float_as_uint(p1.y) * HID2];
            uint2 q2 = *(const uint2*)&xwf[(long)__float_as_uint(p2.y) * HID2];
            uint2 q3 = *(const uint2*)&xwf[(long)__float_as_uint(p3.y) * HID2];
            uint2 q4 = *(const uint2*)&xwf[(long)__float_as_uint(p4.y) * HID2];
            uint2 q5 = *(const uint2*)&xwf[(long)__float_as_uint(p5.y) * HID2];
            uint2 q6 = *(const uint2*)&xwf[(long)__float_as_uint(p6.y) * HID2];
            uint2 q7 = *(const uint2*)&xwf[(long)__float_as_uint(p7.y) * HID2];
            ax = fmaf(p0.x, bflo(q0.x), ax); ay = fmaf(p0.x, bfhi(q0.x), ay);
            az = fmaf(p0.x, bflo(q0.y), az); aw = fmaf(p0.x, bfhi(q0.y), aw);
            ax = fmaf(p1.x, bflo(q1.x), ax); ay = fmaf(p1.x, bfhi(q1.x), ay);
            az = fmaf(p1.x, bflo(q1.y), az); aw = fmaf(p1.x, bfhi(q1.y), aw);
            ax = fmaf(p2.x, bflo(q2.x), ax); ay = fmaf(p2.x, bfhi(q2.x), ay);
            az = fmaf(p2.x, bflo(q2.y), az); aw = fmaf(p2.x, bfhi(q2.y), aw);
            ax = fmaf(p3.x, bflo(q3.x), ax); ay = fmaf(p3.x, bfhi(q3.x), ay);
            az = fmaf(p3.x, bflo(q3.y), az); aw = fmaf(p3.x, bfhi(q3.y), aw);
            ax = fmaf(p4.x, bflo(q4.x), ax); ay = fmaf(p4.x, bfhi(q4.x), ay);
            az = fmaf(p4.x, bflo(q4.y), az); aw = fmaf(p4.x, bfhi(q4.y), aw);
            ax = fmaf(p5.x, bflo(q5.x), ax); ay = fmaf(p5.x, bfhi(q5.x), ay);
            az = fmaf(p5.x, bflo(q5.y), az); aw = fmaf(p5.x, bfhi(q5.y), aw);
            ax = fmaf(p6.x, bflo(q6.x), ax); ay = fmaf(p6.x, bfhi(q6.x), ay);
            az = fmaf(p6.x, bflo(q6.y), az); aw = fmaf(p6.x, bfhi(q6.y), aw);
            ax = fmaf(p7.x, bflo(q7.x), ax); ay = fmaf(p7.x, bfhi(q7.x), ay);
            az = fmaf(p7.x, bflo(q7.y), az); aw = fmaf(p7.x, bfhi(q7.y), aw);
        }
        for (; t < cnt; t++) {
            float2 p = buf[hw][t];
            uint2 q = *(const uint2*)&xwf[(long)__float_as_uint(p.y) * HID2];
            ax = fmaf(p.x, bflo(q.x), ax); ay = fmaf(p.x, bfhi(q.x), ay);
            az = fmaf(p.x, bflo(q.y), az); aw = fmaf(p.x, bfhi(q.y), aw);
        }
    }
    // reduce den across the 32 lanes of this half-wave
    for (int o = 16; o; o >>= 1) den += __shfl_xor(den, o);
    float inv = 1.f / den;
    float v0 = selu_f(fmaf(ax, inv, bias[fl * 4 + 0]));
    float v1 = selu_f(fmaf(ay, inv, bias[fl * 4 + 1]));
    float v2 = selu_f(fmaf(az, inv, bias[fl * 4 + 2]));
    float v3 = selu_f(fmaf(aw, inv, bias[fl * 4 + 3]));
    if (OUTBF16) {
        uint2 o;
        o.x = ((unsigned)f2bf(v1) << 16) | (unsigned)f2bf(v0);
        o.y = ((unsigned)f2bf(v3) << 16) | (unsigned)f2bf(v2);
        *(uint2*)((unsigned short*)outv + (long)node * HID2 + fl * 4) = o;
    } else {
        float4 o = make_float4(v0, v1, v2, v3);
        *(float4*)((float*)outv + (long)node * HID2 + fl * 4) = o;
    }
}

// ---------------- fused pool + fc1 + fc2 + log_softmax: one block per graph ----------------
__global__ __launch_bounds__(256) void pool_head(
        const float* __restrict__ h, const int* __restrict__ batch,
        const float* __restrict__ fc1w, const float* __restrict__ fc1b,
        const float* __restrict__ fc2w, const float* __restrict__ fc2b,
        float* __restrict__ out) {
    __shared__ float pooled_s[HID2];
    __shared__ float part[HID2];
    __shared__ float g_s[NHID];
    int g = blockIdx.x;
    int lo = 0, hi = N_NODES;
    while (lo < hi) { int mid = (lo + hi) >> 1; if (batch[mid] < g) lo = mid + 1; else hi = mid; }
    int start = lo;
    hi = N_NODES;
    while (lo < hi) { int mid = (lo + hi) >> 1; if (batch[mid] < g + 1) lo = mid + 1; else hi = mid; }
    int end = lo;

    int f = threadIdx.x & 127, half = threadIdx.x >> 7;
    float acc = 0.f;
    for (int n = start + half; n < end; n += 2) acc += h[(long)n * HID2 + f];
    if (half == 0) part[f] = acc;
    __syncthreads();
    if (half == 1) {
        float c = (float)(end - start);
        c = c > 1.f ? c : 1.f;
        pooled_s[f] = selu_f((part[f] + acc) / c);
    }
    __syncthreads();
    int j = threadIdx.x;
    if (j < NHID) {
        float a = fc1b[j];
#pragma unroll
        for (int k = 0; k < HID2; k++) a = fmaf(pooled_s[k], fc1w[k * NHID + j], a);
        g_s[j] = selu_f(a);
    }
    __syncthreads();
    if (j == 0) {
        float l0 = fc2b[0], l1 = fc2b[1];
#pragma unroll
        for (int k = 0; k < NHID; k++) {
            float v = g_s[k];
            l0 = fmaf(v, fc2w[2 * k + 0], l0);
            l1 = fmaf(v, fc2w[2 * k + 1], l1);
        }
        float m = fmaxf(l0, l1);
        float lse = m + logf(expf(l0 - m) + expf(l1 - m));
        out[g * 2 + 0] = l0 - lse;
        out[g * 2 + 1] = l1 - lse;
    }
}

extern "C" void kernel_launch(void* const* d_in, const int* in_sizes, int n_in,
                              void* d_out, int out_size, void* d_ws, size_t ws_size,
                              hipStream_t stream) {
    const float* x     = (const float*)d_in[0];
    const int*   ei    = (const int*)d_in[1];
    const int*   batch = (const int*)d_in[2];
    const float* W1    = (const float*)d_in[3];
    const float* as1   = (const float*)d_in[4];
    const float* ad1   = (const float*)d_in[5];
    const float* b1    = (const float*)d_in[6];
    const float* W2    = (const float*)d_in[7];
    const float* as2   = (const float*)d_in[8];
    const float* ad2   = (const float*)d_in[9];
    const float* b2    = (const float*)d_in[10];
    const float* fc1w  = (const float*)d_in[11];
    const float* fc1b  = (const float*)d_in[12];
    const float* fc2w  = (const float*)d_in[13];
    const float* fc2b  = (const float*)d_in[14];
    float* out = (float*)d_out;

    // workspace layout
    const long NH = (long)N_NODES * HID2;        // 6.4M elems
    unsigned short* xwb = (unsigned short*)d_ws;         // NH bf16 (xw, row-major, both layers)
    unsigned short* h1b = xwb + NH;                      // NH bf16 (h1, row-major)
    float*    B2      = (float*)(h1b + NH);              // NH f32 (h2, row-major, for pooling)
    float*    es1     = B2 + NH;
    float*    ed1     = es1 + N_NODES;
    float*    es2     = ed1 + N_NODES;
    float*    ed2     = es2 + N_NODES;
    unsigned* deg     = (unsigned*)(ed2 + N_NODES);
    unsigned* cursor  = deg + N_NODES;
    unsigned* row_ptr = cursor + N_NODES;               // N_NODES+1
    unsigned* csr_src = row_ptr + N_NODES + 1;          // E_TOT
    unsigned short* Wt1 = (unsigned short*)(csr_src + E_TOT);  // 128x768 bf16
    unsigned short* Wt2 = Wt1 + 128 * IN_F;                    // 128x128 bf16

    const int TB = 256;
    const int gNode = (N_NODES + TB - 1) / TB;
    const int gEdge = (N_EDGES + TB - 1) / TB;
    const int gGemm = (N_NODES + 63) / 64;
    const int gAgg  = (N_NODES + 7) / 8;

    // setup (zero deg, weight converts) + CSR build
    setup_k<<<(128 * IN_F + TB - 1) / TB, TB, 0, stream>>>(W1, W2, Wt1, Wt2, deg);
    deg_hist<<<gEdge, TB, 0, stream>>>(ei, deg);
    scan_seed<<<gNode, TB, 0, stream>>>(deg, row_ptr, cursor, csr_src);
    csr_scatter<<<gEdge, TB, 0, stream>>>(ei, cursor, csr_src);

    // ---- layer 1 ----
    gemm_mfma<false, true><<<gGemm, 256, 0, stream>>>(x, Wt1, xwb, N_NODES, IN_F,
                                                      as1, ad1, es1, ed1);
    gat_agg<true><<<gAgg, TB, 0, stream>>>(row_ptr, csr_src, es1, ed1, xwb, b1, h1b);

    // ---- layer 2 ----
    gemm_mfma<true, true><<<gGemm, 256, 0, stream>>>(h1b, Wt2, xwb, N_NODES, HID2,
                                                     as2, ad2, es2, ed2);
    gat_agg<false><<<gAgg, TB, 0, stream>>>(row_ptr, csr_src, es2, ed2, xwb, b2, B2);

    // ---- pool + head (fused) ----
    pool_head<<<N_GRAPHS, 256, 0, stream>>>(B2, batch, fc1w, fc1b, fc2w, fc2b, out);
}

// Round 7
// 483.944 us; speedup vs baseline: 1.4106x; 1.0876x over previous
//
#include <hip/hip_runtime.h>
#include <math.h>

#define N_NODES  50000
#define N_EDGES  800000
#define E_TOT    (N_EDGES + N_NODES)   // 850000 incl self loops
#define N_GRAPHS 128
#define IN_F     768
#define HID2     128
#define NHID     64

typedef __attribute__((ext_vector_type(8))) short bf16x8;
typedef __attribute__((ext_vector_type(4))) float f32x4;
typedef __attribute__((ext_vector_type(4))) unsigned short us4;

__device__ __forceinline__ float selu_f(float x) {
    const float alpha = 1.6732632423543772f;
    const float scale = 1.0507009873554805f;
    return scale * (x > 0.f ? x : alpha * (expf(x) - 1.f));
}

// round-to-nearest-even fp32 -> bf16
__device__ __forceinline__ unsigned short f2bf(float f) {
    unsigned u = __float_as_uint(f);
    u += 0x7FFFu + ((u >> 16) & 1u);
    return (unsigned short)(u >> 16);
}
__device__ __forceinline__ float bflo(unsigned q) { return __uint_as_float(q << 16); }
__device__ __forceinline__ float bfhi(unsigned q) { return __uint_as_float(q & 0xffff0000u); }

// ---------------- setup: zero deg, convert/transpose both weight matrices ----------------
__global__ void setup_k(const float* __restrict__ W1, const float* __restrict__ W2,
                        unsigned short* __restrict__ Wt1, unsigned short* __restrict__ Wt2,
                        unsigned* __restrict__ deg) {
    int i = blockIdx.x * blockDim.x + threadIdx.x;
    if (i < N_NODES) deg[i] = 0u;
    if (i < 128 * IN_F) {
        int n = i / IN_F, k = i - n * IN_F;
        Wt1[i] = f2bf(W1[(long)k * 128 + n]);
    }
    if (i < 128 * HID2) {
        int n = i >> 7, k = i & 127;
        Wt2[i] = f2bf(W2[(long)k * 128 + n]);
    }
}

// ---------------- GEMM: bf16 MFMA, 128x128 tile, BK64, reg-prefetch; fused e_src/e_dst epilogue ----------------
// 4 waves: wave w -> rows (w&1)*64..+64, cols (w>>1)*64..+64; acc 4x4 frags of 16x16.
// es/ed written directly (LDS combine across the two n-half waves) — no atomics, no zero-init.
#define LDA2 72   // padded LDS row stride (bf16): 144 B; frag reads conflict-free
template<bool ABF16, bool OUTBF16>
__global__ __launch_bounds__(256) void gemm_mfma(
        const void* __restrict__ Av, const unsigned short* __restrict__ Bt,
        void* __restrict__ Cv, int M, int K,
        const float* __restrict__ a_s, const float* __restrict__ a_d,
        float* __restrict__ es, float* __restrict__ ed) {
    __shared__ unsigned short As[128 * LDA2];   // 18.4 KB
    __shared__ unsigned short Bs[128 * LDA2];   // 18.4 KB
    __shared__ float es_s[2][128];
    __shared__ float ed_s[2][128];
    const float* Af = (const float*)Av;
    const unsigned short* Ab = (const unsigned short*)Av;
    const int tid  = threadIdx.x;
    const int row0 = blockIdx.x * 128;
    const int w    = tid >> 6;
    const int lane = tid & 63;
    const int quad = lane >> 4;
    const int l16  = lane & 15;
    const int m_off = (w & 1) * 64;   // wave covers 64 rows
    const int n_off = (w >> 1) * 64;  // x 64 cols
    const int nh    = w >> 1;

    f32x4 acc[4][4];
#pragma unroll
    for (int mi = 0; mi < 4; mi++)
#pragma unroll
        for (int ni = 0; ni < 4; ni++)
            acc[mi][ni] = (f32x4){0.f, 0.f, 0.f, 0.f};

    us4 aRc[8];       // f32 path: converted-at-load bf16x4
    bf16x8 aRb[4];    // bf16 path
    bf16x8 bR[4];
    if (ABF16) {
#pragma unroll
        for (int i = 0; i < 4; i++) {
            int p = tid + i * 256;
            int r = p >> 3, c8 = p & 7;
            int gr = row0 + r;
            aRb[i] = (gr < M) ? *(const bf16x8*)&Ab[(long)gr * K + c8 * 8]
                              : (bf16x8){0,0,0,0,0,0,0,0};
        }
    } else {
#pragma unroll
        for (int i = 0; i < 8; i++) {
            int p = tid + i * 256;
            int r = p >> 4, c4 = p & 15;
            int gr = row0 + r;
            float4 v = (gr < M) ? *(const float4*)&Af[(long)gr * K + c4 * 4]
                                : make_float4(0.f, 0.f, 0.f, 0.f);
            us4 o; o.x = f2bf(v.x); o.y = f2bf(v.y); o.z = f2bf(v.z); o.w = f2bf(v.w);
            aRc[i] = o;
        }
    }
#pragma unroll
    for (int i = 0; i < 4; i++) {
        int c = tid + i * 256;
        int n = c >> 3, koff = (c & 7) * 8;
        bR[i] = *(const bf16x8*)&Bt[(long)n * K + koff];
    }

    for (int k0 = 0; k0 < K; k0 += 64) {
        if (ABF16) {
#pragma unroll
            for (int i = 0; i < 4; i++) {
                int p = tid + i * 256;
                int r = p >> 3, c8 = p & 7;
                *(bf16x8*)&As[r * LDA2 + c8 * 8] = aRb[i];
            }
        } else {
#pragma unroll
            for (int i = 0; i < 8; i++) {
                int p = tid + i * 256;
                int r = p >> 4, c4 = p & 15;
                *(us4*)&As[r * LDA2 + c4 * 4] = aRc[i];
            }
        }
#pragma unroll
        for (int i = 0; i < 4; i++) {
            int c = tid + i * 256;
            int n = c >> 3, koff = (c & 7) * 8;
            *(bf16x8*)&Bs[n * LDA2 + koff] = bR[i];
        }
        __syncthreads();

        if (k0 + 64 < K) {
            int k1 = k0 + 64;
            if (ABF16) {
#pragma unroll
                for (int i = 0; i < 4; i++) {
                    int p = tid + i * 256;
                    int r = p >> 3, c8 = p & 7;
                    int gr = row0 + r;
                    aRb[i] = (gr < M) ? *(const bf16x8*)&Ab[(long)gr * K + k1 + c8 * 8]
                                      : (bf16x8){0,0,0,0,0,0,0,0};
                }
            } else {
#pragma unroll
                for (int i = 0; i < 8; i++) {
                    int p = tid + i * 256;
                    int r = p >> 4, c4 = p & 15;
                    int gr = row0 + r;
                    float4 v = (gr < M) ? *(const float4*)&Af[(long)gr * K + k1 + c4 * 4]
                                        : make_float4(0.f, 0.f, 0.f, 0.f);
                    us4 o; o.x = f2bf(v.x); o.y = f2bf(v.y); o.z = f2bf(v.z); o.w = f2bf(v.w);
                    aRc[i] = o;
                }
            }
#pragma unroll
            for (int i = 0; i < 4; i++) {
                int c = tid + i * 256;
                int n = c >> 3, koff = (c & 7) * 8;
                bR[i] = *(const bf16x8*)&Bt[(long)n * K + k1 + koff];
            }
        }

        bf16x8 af[2][4], bfr[2][4];
#pragma unroll
        for (int kk = 0; kk < 2; kk++) {
#pragma unroll
            for (int mi = 0; mi < 4; mi++)
                af[kk][mi] = *(const bf16x8*)&As[(m_off + mi * 16 + l16) * LDA2 + kk * 32 + quad * 8];
#pragma unroll
            for (int ni = 0; ni < 4; ni++)
                bfr[kk][ni] = *(const bf16x8*)&Bs[(n_off + ni * 16 + l16) * LDA2 + kk * 32 + quad * 8];
        }
#pragma unroll
        for (int kk = 0; kk < 2; kk++)
#pragma unroll
            for (int mi = 0; mi < 4; mi++)
#pragma unroll
                for (int ni = 0; ni < 4; ni++)
                    acc[mi][ni] = __builtin_amdgcn_mfma_f32_16x16x32_bf16(
                        af[kk][mi], bfr[kk][ni], acc[mi][ni], 0, 0, 0);
        __syncthreads();
    }

    // attention-vector partials for this lane's 4 cols
    float as_v[4], ad_v[4];
#pragma unroll
    for (int ni = 0; ni < 4; ni++) {
        int col = n_off + ni * 16 + l16;
        as_v[ni] = a_s[col];
        ad_v[ni] = a_d[col];
    }

    // epilogue: D row = m_off+mi*16+quad*4+r, col = n_off+ni*16+l16
#pragma unroll
    for (int mi = 0; mi < 4; mi++)
#pragma unroll
        for (int r = 0; r < 4; r++) {
            int rl  = m_off + mi * 16 + quad * 4 + r;
            int row = row0 + rl;
            float ps = 0.f, pd = 0.f;
#pragma unroll
            for (int ni = 0; ni < 4; ni++) {
                float v = acc[mi][ni][r];
                ps = fmaf(v, as_v[ni], ps);
                pd = fmaf(v, ad_v[ni], pd);
            }
#pragma unroll
            for (int o = 1; o < 16; o <<= 1) {
                ps += __shfl_xor(ps, o);
                pd += __shfl_xor(pd, o);
            }
            if (l16 == 0) {
                es_s[nh][rl] = ps;
                ed_s[nh][rl] = pd;
            }
            if (row < M) {
                if (OUTBF16) {
                    unsigned short* C16 = (unsigned short*)Cv;
#pragma unroll
                    for (int ni = 0; ni < 4; ni++)
                        C16[(long)row * 128 + n_off + ni * 16 + l16] = f2bf(acc[mi][ni][r]);
                } else {
                    float* Cf = (float*)Cv;
#pragma unroll
                    for (int ni = 0; ni < 4; ni++)
                        Cf[(long)row * 128 + n_off + ni * 16 + l16] = acc[mi][ni][r];
                }
            }
        }
    __syncthreads();
    if (tid < 128) {
        int row = row0 + tid;
        if (row < M) {
            es[row] = es_s[0][tid] + es_s[1][tid];
            ed[row] = ed_s[0][tid] + ed_s[1][tid];
        }
    }
}

// ---------------- CSR build (4-kernel chain) ----------------
__global__ void deg_hist(const int* __restrict__ ei, unsigned* __restrict__ deg) {
    int e = blockIdx.x * blockDim.x + threadIdx.x;
    if (e < N_EDGES) atomicAdd(&deg[ei[N_EDGES + e]], 1u);
}

// exclusive scan of (deg+1) -> row_ptr, fused with self-loop seed + cursor init.
__global__ __launch_bounds__(256) void scan_seed(const unsigned* __restrict__ deg,
                                                 unsigned* __restrict__ row_ptr,
                                                 unsigned* __restrict__ cursor,
                                                 unsigned* __restrict__ csr_src) {
    __shared__ unsigned psum_s[4];
    __shared__ unsigned wsum[4];
    int tid = threadIdx.x;
    int wid = tid >> 6, lane = tid & 63;
    int chunk0 = blockIdx.x * 256;

    unsigned psum = 0;
    for (int i = tid; i < chunk0; i += 256) psum += deg[i] + 1u;
    for (int o = 32; o; o >>= 1) psum += __shfl_xor(psum, o);
    if (lane == 0) psum_s[wid] = psum;

    int i = chunk0 + tid;
    unsigned v = (i < N_NODES) ? deg[i] + 1u : 0u;
    unsigned x = v;
    for (int o = 1; o < 64; o <<= 1) {
        unsigned y = __shfl_up(x, o);
        if (lane >= o) x += y;
    }
    if (lane == 63) wsum[wid] = x;
    __syncthreads();
    unsigned base = psum_s[0] + psum_s[1] + psum_s[2] + psum_s[3];
    unsigned wbase = 0;
    for (int k = 0; k < wid; k++) wbase += wsum[k];
    if (i < N_NODES) {
        unsigned rp = base + wbase + x - v;
        row_ptr[i] = rp;
        csr_src[rp] = (unsigned)i;   // self-loop first
        cursor[i] = rp + 1;
        if (i == N_NODES - 1) row_ptr[N_NODES] = rp + v;
    }
}

__global__ void csr_scatter(const int* __restrict__ ei,
                            unsigned* __restrict__ cursor, unsigned* __restrict__ csr_src) {
    int e = blockIdx.x * blockDim.x + threadIdx.x;
    if (e >= N_EDGES) return;
    int d = ei[N_EDGES + e];
    unsigned p = atomicAdd(&cursor[d], 1u);
    csr_src[p] = (unsigned)ei[e];
}

// ---------------- fused GAT tail: one node per HALF-WAVE, unroll-8 row gathers (R2 form) ----------------
template<bool OUTBF16>
__global__ __launch_bounds__(256) void gat_agg(
        const unsigned* __restrict__ row_ptr, const unsigned* __restrict__ csr_src,
        const float* __restrict__ e_src, const float* __restrict__ e_dst,
        const unsigned short* __restrict__ xw, const float* __restrict__ bias,
        void* __restrict__ outv) {
    __shared__ float2 buf[8][32];     // (num, src-bits) per half-wave
    int hw = threadIdx.x >> 5;        // half-wave id 0..7
    int node = blockIdx.x * 8 + hw;
    if (node >= N_NODES) return;
    int fl = threadIdx.x & 31;
    unsigned beg = row_ptr[node];
    int deg = (int)(row_ptr[node + 1] - beg);
    float ed = e_dst[node];
    const unsigned short* xwf = xw + fl * 4;

    float ax = 0.f, ay = 0.f, az = 0.f, aw = 0.f, den = 0.f;
    for (int base = 0; base < deg; base += 32) {
        int i = base + fl;
        float num = 0.f;
        unsigned s = 0u;
        if (i < deg) {
            s = csr_src[beg + i];
            float e = e_src[s] + ed;
            e = e > 0.f ? e : 0.2f * e;
            num = __expf(e);
            den += num;
        }
        float2 pk; pk.x = num; pk.y = __uint_as_float(s);
        buf[hw][fl] = pk;

        int cnt = deg - base; if (cnt > 32) cnt = 32;
        int t = 0;
        for (; t + 8 <= cnt; t += 8) {
            float2 p0 = buf[hw][t + 0];
            float2 p1 = buf[hw][t + 1];
            float2 p2 = buf[hw][t + 2];
            float2 p3 = buf[hw][t + 3];
            float2 p4 = buf[hw][t + 4];
            float2 p5 = buf[hw][t + 5];
            float2 p6 = buf[hw][t + 6];
            float2 p7 = buf[hw][t + 7];
            uint2 q0 = *(const uint2*)&xwf[(long)__float_as_uint(p0.y) * HID2];
            uint2 q1 = *(const uint2*)&xwf[(long)__float_as_uint(p1.y) * HID2];
            uint2 q2 = *(const uint2*)&xwf[(long)__float_as_uint(p2.y) * HID2];
            uint2 q3 = *(const uint2*)&xwf[(long)__float_as_uint(p3.y) * HID2];
            uint2 q4 = *(const uint2*)&xwf[(long)__float_as_uint(p4.y) * HID2];
            uint2 q5 = *(const uint2*)&xwf[(long)__float_as_uint(p5.y) * HID2];
            uint2 q6 = *(const uint2*)&xwf[(long)__float_as_uint(p6.y) * HID2];
            uint2 q7 = *(const uint2*)&xwf[(long)__float_as_uint(p7.y) * HID2];
            ax = fmaf(p0.x, bflo(q0.x), ax); ay = fmaf(p0.x, bfhi(q0.x), ay);
            az = fmaf(p0.x, bflo(q0.y), az); aw = fmaf(p0.x, bfhi(q0.y), aw);
            ax = fmaf(p1.x, bflo(q1.x), ax); ay = fmaf(p1.x, bfhi(q1.x), ay);
            az = fmaf(p1.x, bflo(q1.y), az); aw = fmaf(p1.x, bfhi(q1.y), aw);
            ax = fmaf(p2.x, bflo(q2.x), ax); ay = fmaf(p2.x, bfhi(q2.x), ay);
            az = fmaf(p2.x, bflo(q2.y), az); aw = fmaf(p2.x, bfhi(q2.y), aw);
            ax = fmaf(p3.x, bflo(q3.x), ax); ay = fmaf(p3.x, bfhi(q3.x), ay);
            az = fmaf(p3.x, bflo(q3.y), az); aw = fmaf(p3.x, bfhi(q3.y), aw);
            ax = fmaf(p4.x, bflo(q4.x), ax); ay = fmaf(p4.x, bfhi(q4.x), ay);
            az = fmaf(p4.x, bflo(q4.y), az); aw = fmaf(p4.x, bfhi(q4.y), aw);
            ax = fmaf(p5.x, bflo(q5.x), ax); ay = fmaf(p5.x, bfhi(q5.x), ay);
            az = fmaf(p5.x, bflo(q5.y), az); aw = fmaf(p5.x, bfhi(q5.y), aw);
            ax = fmaf(p6.x, bflo(q6.x), ax); ay = fmaf(p6.x, bfhi(q6.x), ay);
            az = fmaf(p6.x, bflo(q6.y), az); aw = fmaf(p6.x, bfhi(q6.y), aw);
            ax = fmaf(p7.x, bflo(q7.x), ax); ay = fmaf(p7.x, bfhi(q7.x), ay);
            az = fmaf(p7.x, bflo(q7.y), az); aw = fmaf(p7.x, bfhi(q7.y), aw);
        }
        for (; t < cnt; t++) {
            float2 p = buf[hw][t];
            uint2 q = *(const uint2*)&xwf[(long)__float_as_uint(p.y) * HID2];
            ax = fmaf(p.x, bflo(q.x), ax); ay = fmaf(p.x, bfhi(q.x), ay);
            az = fmaf(p.x, bflo(q.y), az); aw = fmaf(p.x, bfhi(q.y), aw);
        }
    }
    // reduce den across the 32 lanes of this half-wave
    for (int o = 16; o; o >>= 1) den += __shfl_xor(den, o);
    float inv = 1.f / den;
    float v0 = selu_f(fmaf(ax, inv, bias[fl * 4 + 0]));
    float v1 = selu_f(fmaf(ay, inv, bias[fl * 4 + 1]));
    float v2 = selu_f(fmaf(az, inv, bias[fl * 4 + 2]));
    float v3 = selu_f(fmaf(aw, inv, bias[fl * 4 + 3]));
    if (OUTBF16) {
        uint2 o;
        o.x = ((unsigned)f2bf(v1) << 16) | (unsigned)f2bf(v0);
        o.y = ((unsigned)f2bf(v3) << 16) | (unsigned)f2bf(v2);
        *(uint2*)((unsigned short*)outv + (long)node * HID2 + fl * 4) = o;
    } else {
        float4 o = make_float4(v0, v1, v2, v3);
        *(float4*)((float*)outv + (long)node * HID2 + fl * 4) = o;
    }
}

// ---------------- fused pool + fc1 + fc2 + log_softmax: one block per graph, float4 loads ----------------
__global__ __launch_bounds__(256) void pool_head(
        const float* __restrict__ h, const int* __restrict__ batch,
        const float* __restrict__ fc1w, const float* __restrict__ fc1b,
        const float* __restrict__ fc2w, const float* __restrict__ fc2b,
        float* __restrict__ out) {
    __shared__ float part4[8][32][4];
    __shared__ float pooled_s[HID2];
    __shared__ float g_s[NHID];
    int g = blockIdx.x;
    int lo = 0, hi = N_NODES;
    while (lo < hi) { int mid = (lo + hi) >> 1; if (batch[mid] < g) lo = mid + 1; else hi = mid; }
    int start = lo;
    hi = N_NODES;
    while (lo < hi) { int mid = (lo + hi) >> 1; if (batch[mid] < g + 1) lo = mid + 1; else hi = mid; }
    int end = lo;

    int l = threadIdx.x & 31, half = threadIdx.x >> 5;   // 8 row-groups x 32 feature-quads
    const float4* h4 = (const float4*)h;
    float a0 = 0.f, a1 = 0.f, a2 = 0.f, a3 = 0.f;
    for (int n = start + half; n < end; n += 8) {
        float4 v = h4[(long)n * 32 + l];
        a0 += v.x; a1 += v.y; a2 += v.z; a3 += v.w;
    }
    part4[half][l][0] = a0; part4[half][l][1] = a1;
    part4[half][l][2] = a2; part4[half][l][3] = a3;
    __syncthreads();
    if (threadIdx.x < 32) {
        int q = threadIdx.x;
        float s0 = 0.f, s1 = 0.f, s2 = 0.f, s3 = 0.f;
#pragma unroll
        for (int k = 0; k < 8; k++) {
            s0 += part4[k][q][0]; s1 += part4[k][q][1];
            s2 += part4[k][q][2]; s3 += part4[k][q][3];
        }
        float c = (float)(end - start);
        c = c > 1.f ? c : 1.f;
        float invc = 1.f / c;
        pooled_s[q * 4 + 0] = selu_f(s0 * invc);
        pooled_s[q * 4 + 1] = selu_f(s1 * invc);
        pooled_s[q * 4 + 2] = selu_f(s2 * invc);
        pooled_s[q * 4 + 3] = selu_f(s3 * invc);
    }
    __syncthreads();
    int j = threadIdx.x;
    if (j < NHID) {
        float a = fc1b[j];
#pragma unroll
        for (int k = 0; k < HID2; k++) a = fmaf(pooled_s[k], fc1w[k * NHID + j], a);
        g_s[j] = selu_f(a);
    }
    __syncthreads();
    if (j == 0) {
        float l0 = fc2b[0], l1 = fc2b[1];
#pragma unroll
        for (int k = 0; k < NHID; k++) {
            float v = g_s[k];
            l0 = fmaf(v, fc2w[2 * k + 0], l0);
            l1 = fmaf(v, fc2w[2 * k + 1], l1);
        }
        float m = fmaxf(l0, l1);
        float lse = m + logf(expf(l0 - m) + expf(l1 - m));
        out[g * 2 + 0] = l0 - lse;
        out[g * 2 + 1] = l1 - lse;
    }
}

extern "C" void kernel_launch(void* const* d_in, const int* in_sizes, int n_in,
                              void* d_out, int out_size, void* d_ws, size_t ws_size,
                              hipStream_t stream) {
    const float* x     = (const float*)d_in[0];
    const int*   ei    = (const int*)d_in[1];
    const int*   batch = (const int*)d_in[2];
    const float* W1    = (const float*)d_in[3];
    const float* as1   = (const float*)d_in[4];
    const float* ad1   = (const float*)d_in[5];
    const float* b1    = (const float*)d_in[6];
    const float* W2    = (const float*)d_in[7];
    const float* as2   = (const float*)d_in[8];
    const float* ad2   = (const float*)d_in[9];
    const float* b2    = (const float*)d_in[10];
    const float* fc1w  = (const float*)d_in[11];
    const float* fc1b  = (const float*)d_in[12];
    const float* fc2w  = (const float*)d_in[13];
    const float* fc2b  = (const float*)d_in[14];
    float* out = (float*)d_out;

    // workspace layout
    const long NH = (long)N_NODES * HID2;        // 6.4M elems
    unsigned short* xwb = (unsigned short*)d_ws;         // NH bf16 (xw, row-major, both layers)
    unsigned short* h1b = xwb + NH;                      // NH bf16 (h1, row-major)
    float*    B2      = (float*)(h1b + NH);              // NH f32 (h2, row-major, for pooling)
    float*    es1     = B2 + NH;
    float*    ed1     = es1 + N_NODES;
    float*    es2     = ed1 + N_NODES;
    float*    ed2     = es2 + N_NODES;
    unsigned* deg     = (unsigned*)(ed2 + N_NODES);
    unsigned* cursor  = deg + N_NODES;
    unsigned* row_ptr = cursor + N_NODES;               // N_NODES+1
    unsigned* csr_src = row_ptr + N_NODES + 1;          // E_TOT
    unsigned short* Wt1 = (unsigned short*)(csr_src + E_TOT);  // 128x768 bf16
    unsigned short* Wt2 = Wt1 + 128 * IN_F;                    // 128x128 bf16

    const int TB = 256;
    const int gNode = (N_NODES + TB - 1) / TB;
    const int gEdge = (N_EDGES + TB - 1) / TB;
    const int gGemm = (N_NODES + 127) / 128;
    const int gAgg  = (N_NODES + 7) / 8;

    // setup (zero deg, weight converts) + CSR build
    setup_k<<<(128 * IN_F + TB - 1) / TB, TB, 0, stream>>>(W1, W2, Wt1, Wt2, deg);
    deg_hist<<<gEdge, TB, 0, stream>>>(ei, deg);
    scan_seed<<<gNode, TB, 0, stream>>>(deg, row_ptr, cursor, csr_src);
    csr_scatter<<<gEdge, TB, 0, stream>>>(ei, cursor, csr_src);

    // ---- layer 1 ----
    gemm_mfma<false, true><<<gGemm, 256, 0, stream>>>(x, Wt1, xwb, N_NODES, IN_F,
                                                      as1, ad1, es1, ed1);
    gat_agg<true><<<gAgg, TB, 0, stream>>>(row_ptr, csr_src, es1, ed1, xwb, b1, h1b);

    // ---- layer 2 ----
    gemm_mfma<true, true><<<gGemm, 256, 0, stream>>>(h1b, Wt2, xwb, N_NODES, HID2,
                                                     as2, ad2, es2, ed2);
    gat_agg<false><<<gAgg, TB, 0, stream>>>(row_ptr, csr_src, es2, ed2, xwb, b2, B2);

    // ---- pool + head (fused) ----
    pool_head<<<N_GRAPHS, 256, 0, stream>>>(B2, batch, fc1w, fc1b, fc2w, fc2b, out);
}